// Round 7
// baseline (3273.830 us; speedup 1.0000x reference)
//
#include <hip/hip_runtime.h>
#include <stdint.h>

#define SS 64
#define BB 64
#define TT 100
#define HOPC 256
#define NFC 256
#define GCC 256
#define ICC 512
#define NC (1.0f/127.0f)
#define NBLK 64       // one block per chain
#define NTHR 512      // 8 waves: lane = (row, g), row=tid>>3, g=tid&7

// f16 weight arena offsets (in halves; same order as inputs 6..19)
#define OFF_FW     0
#define OFF_FWGLU  8192
#define OFF_G1IH   12288
#define OFF_G1HH   36864
#define OFF_GLU1   49152
#define OFF_G2IH   53248
#define OFF_G2HH   77824
#define OFF_GLU2   90112
#define OFF_G3IH   94208
#define OFF_G3HH   118784
#define OFF_GLU3   131072
#define OFF_SKIPD  135168
#define OFF_SKIPG  176128
#define OFF_OUT    192512
#define W_TOTAL    200704
#define XALL_F32   (TT * BB * HOPC)   // 1,638,400 floats

// LDS weight strides (halves), padded to de-phase banks
#define SKD_ST 328
#define SKG_ST 136

typedef _Float16 f16;
typedef _Float16 h2 __attribute__((ext_vector_type(2)));
union U16 { uint4 u; h2 h[4]; };

#if __has_builtin(__builtin_amdgcn_fdot2)
#define FDOT2(a, b, c) __builtin_amdgcn_fdot2((a), (b), (c), false)
#else
#define FDOT2(a, b, c) ((c) + (float)(a)[0] * (float)(b)[0] + (float)(a)[1] * (float)(b)[1])
#endif

// ---------------- threefry2x32 core (Random123-KAT verified) ----------------
__device__ __forceinline__ uint32_t rotl32(uint32_t x, int r) {
    return (x << r) | (x >> (32 - r));
}

__device__ __forceinline__ void tf2x32(uint32_t k0, uint32_t k1, uint32_t c0, uint32_t c1,
                                       uint32_t& o0, uint32_t& o1) {
    uint32_t k2 = k0 ^ k1 ^ 0x1BD11BDAu;
    uint32_t x0 = c0 + k0, x1 = c1 + k1;
    x0 += x1; x1 = rotl32(x1, 13); x1 ^= x0;
    x0 += x1; x1 = rotl32(x1, 15); x1 ^= x0;
    x0 += x1; x1 = rotl32(x1, 26); x1 ^= x0;
    x0 += x1; x1 = rotl32(x1, 6);  x1 ^= x0;
    x0 += k1; x1 += k2 + 1u;
    x0 += x1; x1 = rotl32(x1, 17); x1 ^= x0;
    x0 += x1; x1 = rotl32(x1, 29); x1 ^= x0;
    x0 += x1; x1 = rotl32(x1, 16); x1 ^= x0;
    x0 += x1; x1 = rotl32(x1, 24); x1 ^= x0;
    x0 += k2; x1 += k0 + 2u;
    x0 += x1; x1 = rotl32(x1, 13); x1 ^= x0;
    x0 += x1; x1 = rotl32(x1, 15); x1 ^= x0;
    x0 += x1; x1 = rotl32(x1, 26); x1 ^= x0;
    x0 += x1; x1 = rotl32(x1, 6);  x1 ^= x0;
    x0 += k0; x1 += k1 + 3u;
    x0 += x1; x1 = rotl32(x1, 17); x1 ^= x0;
    x0 += x1; x1 = rotl32(x1, 29); x1 ^= x0;
    x0 += x1; x1 = rotl32(x1, 16); x1 ^= x0;
    x0 += x1; x1 = rotl32(x1, 24); x1 ^= x0;
    x0 += k1; x1 += k2 + 4u;
    x0 += x1; x1 = rotl32(x1, 13); x1 ^= x0;
    x0 += x1; x1 = rotl32(x1, 15); x1 ^= x0;
    x0 += x1; x1 = rotl32(x1, 26); x1 ^= x0;
    x0 += x1; x1 = rotl32(x1, 6);  x1 ^= x0;
    x0 += k2; x1 += k0 + 5u;
    o0 = x0; o1 = x1;
}

// jax_threefry_partitionable semantics: bits(m) = x0^x1 of block (0, m)
__device__ __forceinline__ float unifP(uint32_t k0, uint32_t k1, uint32_t m) {
    uint32_t o0, o1;
    tf2x32(k0, k1, 0u, m, o0, o1);
    uint32_t bits = o0 ^ o1;
    return __uint_as_float((bits >> 9) | 0x3f800000u) - 1.0f;
}

__device__ __forceinline__ float clipf(float v) { return fminf(1.0f, fmaxf(-1.0f, v)); }
__device__ __forceinline__ float sigmf(float v) { return 1.0f / (1.0f + __expf(-v)); }
__device__ __forceinline__ float noiseu(float v, float u) {
    return clipf(v + (u - 0.5f) * NC);
}

// ---------------- f16 dot helpers (fp32 accumulate via v_dot2) ----------------
__device__ __forceinline__ float dotK16(const U16* w, const f16* x, float acc) {
    U16 xa, xb;
    xa.u = *(const uint4*)x;
    xb.u = *(const uint4*)(x + 8);
#pragma unroll
    for (int i = 0; i < 4; ++i) acc = FDOT2(w[0].h[i], xa.h[i], acc);
#pragma unroll
    for (int i = 0; i < 4; ++i) acc = FDOT2(w[1].h[i], xb.h[i], acc);
    return acc;
}
__device__ __forceinline__ float dotK8(const U16& w, const f16* x, float acc) {
    U16 xa;
    xa.u = *(const uint4*)x;
#pragma unroll
    for (int i = 0; i < 4; ++i) acc = FDOT2(w.h[i], xa.h[i], acc);
    return acc;
}

template<int NR>
__device__ __forceinline__ void red8(float (&a)[NR]) {
#pragma unroll
    for (int j = 0; j < NR; ++j) {
        float v = a[j];
        v += __shfl_xor(v, 1);
        v += __shfl_xor(v, 2);
        v += __shfl_xor(v, 4);
        a[j] = v;
    }
}

// ---------------- register weight structs + loaders ----------------
struct WF1  { U16 w[2]; };                        // K=128, NR=1
struct WGRU { U16 wih[6]; U16 whh[3]; U16 glu; }; // 40 VGPRs

__device__ __forceinline__ void ldF1(const f16* W, int row, int g, WF1& r) {
    const f16* p = W + row * 128 + g * 16;
    r.w[0].u = *(const uint4*)p;
    r.w[1].u = *(const uint4*)(p + 8);
}
__device__ __forceinline__ void ldF2(const f16* W, int row, int g, U16& r) {
    r.u = *(const uint4*)(W + row * 64 + g * 8);
}
__device__ __forceinline__ void ldGRU(const f16* Wih, const f16* Whh, const f16* Glu,
                                      int row, int g, WGRU& r) {
#pragma unroll
    for (int j = 0; j < 3; ++j) {
        const f16* p = Wih + (row + 64 * j) * 128 + g * 16;
        r.wih[2 * j].u     = *(const uint4*)p;
        r.wih[2 * j + 1].u = *(const uint4*)(p + 8);
        r.whh[j].u = *(const uint4*)(Whh + (row + 64 * j) * 64 + g * 8);
    }
    r.glu.u = *(const uint4*)(Glu + row * 64 + g * 8);
}

// ---------------- weight convert to f16 (flat, same layout) ----------------
struct SrcW { const float* p[14]; };

__global__ __launch_bounds__(256) void fargan_cvtw(SrcW s, f16* __restrict__ dst) {
    const int offs[15] = {0, 8192, 12288, 36864, 49152, 53248, 77824, 90112,
                          94208, 118784, 131072, 135168, 176128, 192512, 200704};
    int i = blockIdx.x * 256 + threadIdx.x;
    if (i >= W_TOTAL) return;
    int sgi = 0;
#pragma unroll
    for (int t = 1; t < 14; ++t) sgi += (i >= offs[t]);
    dst[i] = (f16)s.p[sgi][i - offs[sgi]];
}

// ---------------- frame input network (fp32) ----------------
__global__ __launch_bounds__(256) void fargan_frame(
    const float* __restrict__ features, const float* __restrict__ gfeat,
    const float* __restrict__ W1, const float* __restrict__ ib1,
    const float* __restrict__ W2, const float* __restrict__ ib2,
    float* __restrict__ xall)
{
    __shared__ __align__(16) float cat[16][ICC];
    __shared__ __align__(16) float zb[16][ICC];
    const int tid = threadIdx.x;
    const int t = blockIdx.x >> 2;
    const int q = blockIdx.x & 3;

    for (int bb = 0; bb < 16; ++bb) {
        int b = q * 16 + bb;
        for (int c = tid; c < ICC; c += 256) {
            float v = (c < NFC) ? features[b * NFC * TT + c * TT + t]
                                : gfeat[b * GCC + (c - NFC)];
            cat[bb][c] = v;
        }
    }
    __syncthreads();

    {
        int rg = tid & 63, bg = tid >> 6;
        int n0 = rg * 8, bb0 = bg * 4;
        float acc[8][4];
#pragma unroll
        for (int r = 0; r < 8; ++r)
#pragma unroll
            for (int j = 0; j < 4; ++j) acc[r][j] = 0.f;
        for (int k = 0; k < ICC; k += 4) {
            float4 cv[4];
#pragma unroll
            for (int j = 0; j < 4; ++j) cv[j] = *(const float4*)&cat[bb0 + j][k];
#pragma unroll
            for (int r = 0; r < 8; ++r) {
                float4 wv = *(const float4*)&W1[(n0 + r) * ICC + k];
#pragma unroll
                for (int j = 0; j < 4; ++j)
                    acc[r][j] += wv.x * cv[j].x + wv.y * cv[j].y + wv.z * cv[j].z + wv.w * cv[j].w;
            }
        }
#pragma unroll
        for (int r = 0; r < 8; ++r) {
            float bias = ib1[n0 + r];
#pragma unroll
            for (int j = 0; j < 4; ++j)
                zb[bb0 + j][n0 + r] = tanhf(acc[r][j] + bias);
        }
    }
    __syncthreads();

    {
        int rg = tid & 63, bg = tid >> 6;
        int n0 = rg * 4, bb0 = bg * 4;
        float acc[4][4];
#pragma unroll
        for (int r = 0; r < 4; ++r)
#pragma unroll
            for (int j = 0; j < 4; ++j) acc[r][j] = 0.f;
        for (int k = 0; k < ICC; k += 4) {
            float4 cv[4];
#pragma unroll
            for (int j = 0; j < 4; ++j) cv[j] = *(const float4*)&zb[bb0 + j][k];
#pragma unroll
            for (int r = 0; r < 4; ++r) {
                float4 wv = *(const float4*)&W2[(n0 + r) * ICC + k];
#pragma unroll
                for (int j = 0; j < 4; ++j)
                    acc[r][j] += wv.x * cv[j].x + wv.y * cv[j].y + wv.z * cv[j].z + wv.w * cv[j].w;
            }
        }
#pragma unroll
        for (int r = 0; r < 4; ++r) {
            float bias = ib2[n0 + r];
#pragma unroll
            for (int j = 0; j < 4; ++j) {
                int b = q * 16 + bb0 + j;
                xall[(t * BB + b) * HOPC + n0 + r] = acc[r][j] + bias;
            }
        }
    }
}

// ---------------- sequential chain: weights register/LDS resident ----------
__global__ __launch_bounds__(512, 2) void fargan_seq(
    const float* __restrict__ xall, const f16* __restrict__ wh,
    float* __restrict__ outp)
{
    const int tid = threadIdx.x;
    const int row = tid >> 3;
    const int g = tid & 7;
    const int bg = blockIdx.x;          // chain id

    // fp32 state + uniforms
    __shared__ __align__(16) float XS[128];               // xsub|s3 (delay line)
    __shared__ __align__(16) float H1[64], H2[64], H3[64];
    __shared__ __align__(16) float UNF[704];
    // f16 matvec operand mirrors
    __shared__ __align__(16) f16 XH[128];                 // xsub|s3
    __shared__ __align__(16) f16 SKXH[320];               // g1|g2|g3|fw|prevN
    __shared__ __align__(16) f16 H1H[64], H2H[64], H3H[64];
    __shared__ __align__(16) f16 TWH[64], HNH[64];
    __shared__ __align__(16) f16 SPNH[128], SKVH[128];
    // LDS-resident big weights (padded strides)
    __shared__ __align__(16) f16 LSKD[128 * SKD_ST];      // skip_dense 128x320
    __shared__ __align__(16) f16 LSKG[128 * SKG_ST];      // skip_glu  128x128
    __shared__ uint32_t kkb[20];        // kk[j] = (kkb[2j], kkb[2j+1])

    // ---- one-time: stage big weights into LDS (16B chunks, aligned)
    for (int i = tid; i < 128 * 40; i += NTHR) {          // skip_dense: 40 x uint4 per row
        int r = i / 40, c = (i - r * 40) * 8;
        *(uint4*)&LSKD[r * SKD_ST + c] = *(const uint4*)(wh + OFF_SKIPD + r * 320 + c);
    }
    for (int i = tid; i < 128 * 16; i += NTHR) {          // skip_glu: 16 x uint4 per row
        int r = i >> 4, c = (i & 15) * 8;
        *(uint4*)&LSKG[r * SKG_ST + c] = *(const uint4*)(wh + OFF_SKIPG + r * 128 + c);
    }

    // ---- one-time: register-resident weight slices (140 VGPRs)
    WF1 rF1;  ldF1(wh + OFF_FW, row, g, rF1);
    U16 rF2;  ldF2(wh + OFF_FWGLU, row, g, rF2);
    WGRU rG1; ldGRU(wh + OFF_G1IH, wh + OFF_G1HH, wh + OFF_GLU1, row, g, rG1);
    WGRU rG2; ldGRU(wh + OFF_G2IH, wh + OFF_G2HH, wh + OFF_GLU2, row, g, rG2);
    WGRU rG3; ldGRU(wh + OFF_G3IH, wh + OFF_G3HH, wh + OFF_GLU3, row, g, rG3);
    WF1 rOUT; ldF1(wh + OFF_OUT, row, g, rOUT);

    float prevO = 0.f;
    if (g == 0) {
        H1[row] = 0.f; H2[row] = 0.f; H3[row] = 0.f;
        H1H[row] = (f16)0.f; H2H[row] = (f16)0.f; H3H[row] = (f16)0.f;
        XS[row] = 0.f; XS[64 + row] = 0.f;
        XH[row] = (f16)0.f; XH[64 + row] = (f16)0.f;
    }
    if (tid < 10) {
        uint32_t f0, f1; tf2x32(0u, 1u, 0u, 0u, f0, f1);           // fold_in(key(1), 0)
        uint32_t A, Bv;  tf2x32(f0, f1, 0u, (uint32_t)tid, A, Bv); // foldlike split
        kkb[2 * tid] = A; kkb[2 * tid + 1] = Bv;
    }
    __syncthreads();

    for (int t = 0; t < TT; ++t) {
        for (int s = 0; s < 4; ++s) {
            const int idx = t * 4 + s;

            // ---- A: stage reads; precompute all uniforms for this subframe
            float xo = XS[row];
            float xv = xall[(t * BB + bg) * HOPC + s * SS + row];
#pragma unroll
            for (int rep = 0; rep < 2; ++rep) {
                int j = tid + rep * 512;
                if (j < 704) {
                    int sl = j >> 6;
                    uint32_t m = (sl < 9) ? (uint32_t)(bg * 64 + (j & 63))
                                          : (uint32_t)(bg * 128 + (j - 576));
                    int kx = (sl < 9) ? 2 * sl : 18;
                    UNF[j] = unifP(kkb[kx], kkb[kx + 1], m);
                }
            }
            __syncthreads();

            // ---- B: write xsub/s3/prevN (state + f16 mirrors)
            if (g == 0) {
                XS[64 + row] = xo;           XH[64 + row] = (f16)xo;
                float xs = noiseu(xv, UNF[row]);
                XS[row] = xs;                XH[row] = (f16)xs;
                SKXH[256 + row] = (f16)noiseu(prevO, UNF[64 + row]);
            }
            __syncthreads();

            // ---- FW1: tw = tanh(fw_W @ [xsub; s3])
            float a1[1] = {0};
            a1[0] = dotK16(rF1.w, XH + g * 16, a1[0]);
            red8<1>(a1);
            float twv = tanhf(a1[0]);
            if (g == 0) TWH[row] = (f16)twv;
            __syncthreads();

            // ---- FW2: fw = noise(tw * sigm(fw_glu @ tw))
            float a2[1] = {0};
            a2[0] = dotK8(rF2, TWH + g * 8, a2[0]);
            red8<1>(a2);
            if (g == 0) SKXH[192 + row] = (f16)noiseu(twv * sigmf(a2[0]), UNF[128 + row]);
            __syncthreads();

            // ---- GRU + GLU x3 (weights in registers)
#define GRU_GLU(RG, XIN, HBUF, HH, UH, UG, GOFF)                                           \
            {                                                                               \
                float ai[3] = {0, 0, 0};                                                    \
                const f16* xin = (XIN);                                                     \
                _Pragma("unroll")                                                           \
                for (int j = 0; j < 3; ++j) ai[j] = dotK16(&RG.wih[2 * j], xin, ai[j]);     \
                float ah[3] = {0, 0, 0};                                                    \
                const f16* xh = HH + g * 8;                                                 \
                _Pragma("unroll")                                                           \
                for (int j = 0; j < 3; ++j) ah[j] = dotK8(RG.whh[j], xh, ah[j]);            \
                red8<3>(ai); red8<3>(ah);                                                   \
                float hold = HBUF[row];                                                     \
                float r  = sigmf(ai[0] + ah[0]);                                            \
                float z  = sigmf(ai[1] + ah[1]);                                            \
                float nn = tanhf(ai[2] + r * ah[2]);                                        \
                float hnew = (1.f - z) * nn + z * hold;                                     \
                float hNv = noiseu(hnew, UNF[(UH) + row]);                                  \
                __syncthreads();                                                            \
                if (g == 0) { HBUF[row] = hnew; HH[row] = (f16)hnew; HNH[row] = (f16)hNv; } \
                __syncthreads();                                                            \
                float ag[1] = {0};                                                          \
                ag[0] = dotK8(RG.glu, HNH + g * 8, ag[0]);                                  \
                red8<1>(ag);                                                                \
                if (g == 0) SKXH[(GOFF) + row] =                                            \
                    (f16)noiseu(hNv * sigmf(ag[0]), UNF[(UG) + row]);                       \
            }                                                                               \
            __syncthreads();

            GRU_GLU(rG1, SKXH + 192 + g * 16, H1, H1H, 192, 256, 0)
            GRU_GLU(rG2, (g < 4 ? SKXH + g * 16 : SKXH + 256 + (g - 4) * 16), H2, H2H, 320, 384, 64)
            GRU_GLU(rG3, (g < 4 ? SKXH + 64 + g * 16 : SKXH + 256 + (g - 4) * 16), H3, H3H, 448, 512, 128)
#undef GRU_GLU

            // ---- SKIP: spN = noise(tanh(skip_dense @ SKXH[0:320]))  [weights in LDS]
            float as[2] = {0, 0};
            {
                const f16* xs = SKXH + g * 40;
#pragma unroll
                for (int j = 0; j < 2; ++j) {
                    const f16* wrow = LSKD + (row + 64 * j) * SKD_ST + g * 40;
#pragma unroll
                    for (int i = 0; i < 5; ++i)
                        as[j] = dotK8(*(const U16*)(wrow + 8 * i), xs + 8 * i, as[j]);
                }
            }
            red8<2>(as);
            float sp0 = noiseu(tanhf(as[0]), UNF[576 + row]);
            float sp1 = noiseu(tanhf(as[1]), UNF[640 + row]);
            if (g == 0) { SPNH[row] = (f16)sp0; SPNH[64 + row] = (f16)sp1; }
            __syncthreads();

            // ---- SG: skip = spN * sigm(skip_glu @ spN)  [weights in LDS]
            float ag2[2] = {0, 0};
            {
                const f16* xg = SPNH + g * 16;
#pragma unroll
                for (int j = 0; j < 2; ++j) {
                    const f16* wrow = LSKG + (row + 64 * j) * SKG_ST + g * 16;
                    ag2[j] = dotK8(*(const U16*)wrow, xg, ag2[j]);
                    ag2[j] = dotK8(*(const U16*)(wrow + 8), xg + 8, ag2[j]);
                }
            }
            red8<2>(ag2);
            if (g == 0) {
                SKVH[row]      = (f16)(sp0 * sigmf(ag2[0]));
                SKVH[64 + row] = (f16)(sp1 * sigmf(ag2[1]));
            }
            __syncthreads();

            // ---- OUT: o = tanh(out_W @ skip); update keys
            float ao[1] = {0};
            ao[0] = dotK16(rOUT.w, SKVH + g * 16, ao[0]);
            red8<1>(ao);
            float o = tanhf(ao[0]);
            prevO = o;
            if (g == 0) outp[bg * (TT * HOPC) + t * HOPC + s * SS + row] = o;
            if (tid < 10 && idx + 1 < 400) {
                uint32_t f0, f1; tf2x32(0u, 1u, 0u, (uint32_t)(idx + 1), f0, f1);
                uint32_t A, Bv;  tf2x32(f0, f1, 0u, (uint32_t)tid, A, Bv);
                kkb[2 * tid] = A; kkb[2 * tid + 1] = Bv;
            }
            __syncthreads();
        }
    }
}

extern "C" void kernel_launch(void* const* d_in, const int* in_sizes, int n_in,
                              void* d_out, int out_size, void* d_ws, size_t ws_size,
                              hipStream_t stream) {
    const float* features = (const float*)d_in[0];
    const float* gfeat    = (const float*)d_in[1];
    const float* W1       = (const float*)d_in[2];
    const float* ib1      = (const float*)d_in[3];
    const float* W2       = (const float*)d_in[4];
    const float* ib2      = (const float*)d_in[5];

    float* xall = (float*)d_ws;                    // 6.55 MB
    f16*   wh   = (f16*)(xall + XALL_F32);         // 0.40 MB, 16B-aligned
    float* outp = (float*)d_out;

    SrcW sw;
    for (int i = 0; i < 14; ++i) sw.p[i] = (const float*)d_in[6 + i];

    hipLaunchKernelGGL(fargan_cvtw, dim3((W_TOTAL + 255) / 256), dim3(256), 0, stream, sw, wh);
    hipLaunchKernelGGL(fargan_frame, dim3(TT * 4), dim3(256), 0, stream,
                       features, gfeat, W1, ib1, W2, ib2, xall);
    hipLaunchKernelGGL(fargan_seq, dim3(NBLK), dim3(NTHR), 0, stream, xall, wh, outp);
}

// Round 8
// 2845.003 us; speedup vs baseline: 1.1507x; 1.1507x over previous
//
#include <hip/hip_runtime.h>
#include <stdint.h>

#define SS 64
#define BB 64
#define TT 100
#define HOPC 256
#define NFC 256
#define GCC 256
#define ICC 512
#define NC (1.0f/127.0f)
#define NBLK 64       // one block per chain
#define NTHR 512      // 8 waves: lane = (row, g), row=tid>>3, g=tid&7

// f16 weight arena offsets (in halves; same order as inputs 6..19)
#define OFF_FW     0
#define OFF_FWGLU  8192
#define OFF_G1IH   12288
#define OFF_G1HH   36864
#define OFF_GLU1   49152
#define OFF_G2IH   53248
#define OFF_G2HH   77824
#define OFF_GLU2   90112
#define OFF_G3IH   94208
#define OFF_G3HH   118784
#define OFF_GLU3   131072
#define OFF_SKIPD  135168
#define OFF_SKIPG  176128
#define OFF_OUT    192512
#define W_TOTAL    200704
#define XALL_F32   (TT * BB * HOPC)   // 1,638,400 floats

typedef _Float16 f16;
typedef _Float16 h2 __attribute__((ext_vector_type(2)));
union U16 { uint4 u; h2 h[4]; };

#if __has_builtin(__builtin_amdgcn_fdot2)
#define FDOT2(a, b, c) __builtin_amdgcn_fdot2((a), (b), (c), false)
#else
#define FDOT2(a, b, c) ((c) + (float)(a)[0] * (float)(b)[0] + (float)(a)[1] * (float)(b)[1])
#endif

// ---------------- threefry2x32 core (Random123-KAT verified) ----------------
__device__ __forceinline__ uint32_t rotl32(uint32_t x, int r) {
    return (x << r) | (x >> (32 - r));
}

__device__ __forceinline__ void tf2x32(uint32_t k0, uint32_t k1, uint32_t c0, uint32_t c1,
                                       uint32_t& o0, uint32_t& o1) {
    uint32_t k2 = k0 ^ k1 ^ 0x1BD11BDAu;
    uint32_t x0 = c0 + k0, x1 = c1 + k1;
    x0 += x1; x1 = rotl32(x1, 13); x1 ^= x0;
    x0 += x1; x1 = rotl32(x1, 15); x1 ^= x0;
    x0 += x1; x1 = rotl32(x1, 26); x1 ^= x0;
    x0 += x1; x1 = rotl32(x1, 6);  x1 ^= x0;
    x0 += k1; x1 += k2 + 1u;
    x0 += x1; x1 = rotl32(x1, 17); x1 ^= x0;
    x0 += x1; x1 = rotl32(x1, 29); x1 ^= x0;
    x0 += x1; x1 = rotl32(x1, 16); x1 ^= x0;
    x0 += x1; x1 = rotl32(x1, 24); x1 ^= x0;
    x0 += k2; x1 += k0 + 2u;
    x0 += x1; x1 = rotl32(x1, 13); x1 ^= x0;
    x0 += x1; x1 = rotl32(x1, 15); x1 ^= x0;
    x0 += x1; x1 = rotl32(x1, 26); x1 ^= x0;
    x0 += x1; x1 = rotl32(x1, 6);  x1 ^= x0;
    x0 += k0; x1 += k1 + 3u;
    x0 += x1; x1 = rotl32(x1, 17); x1 ^= x0;
    x0 += x1; x1 = rotl32(x1, 29); x1 ^= x0;
    x0 += x1; x1 = rotl32(x1, 16); x1 ^= x0;
    x0 += x1; x1 = rotl32(x1, 24); x1 ^= x0;
    x0 += k1; x1 += k2 + 4u;
    x0 += x1; x1 = rotl32(x1, 13); x1 ^= x0;
    x0 += x1; x1 = rotl32(x1, 15); x1 ^= x0;
    x0 += x1; x1 = rotl32(x1, 26); x1 ^= x0;
    x0 += x1; x1 = rotl32(x1, 6);  x1 ^= x0;
    x0 += k2; x1 += k0 + 5u;
    o0 = x0; o1 = x1;
}

// jax_threefry_partitionable semantics: bits(m) = x0^x1 of block (0, m)
__device__ __forceinline__ float unifP(uint32_t k0, uint32_t k1, uint32_t m) {
    uint32_t o0, o1;
    tf2x32(k0, k1, 0u, m, o0, o1);
    uint32_t bits = o0 ^ o1;
    return __uint_as_float((bits >> 9) | 0x3f800000u) - 1.0f;
}

__device__ __forceinline__ float clipf(float v) { return fminf(1.0f, fmaxf(-1.0f, v)); }
__device__ __forceinline__ float noiseu(float v, float u) {
    return clipf(v + (u - 0.5f) * NC);
}
__device__ __forceinline__ float sigmf(float v) {
    return __fdividef(1.0f, 1.0f + __expf(-v));
}
__device__ __forceinline__ float tanhfast(float x) {
    float ax = fminf(fabsf(x), 15.0f);
    float e = __expf(2.0f * ax);
    float r = __fdividef(e - 1.0f, e + 1.0f);
    return copysignf(r, x);
}

// ---------------- DPP 8-lane reduction (VALU-only, no DS pipe) --------------
__device__ __forceinline__ float red8dpp(float v) {
    int t;
    t = __builtin_amdgcn_update_dpp(0, __float_as_int(v), 0xB1, 0xF, 0xF, true);  // quad xor1
    v += __int_as_float(t);
    t = __builtin_amdgcn_update_dpp(0, __float_as_int(v), 0x4E, 0xF, 0xF, true);  // quad xor2
    v += __int_as_float(t);
    t = __builtin_amdgcn_update_dpp(0, __float_as_int(v), 0x141, 0xF, 0xF, true); // half-row mirror
    v += __int_as_float(t);
    return v;   // all 8 lanes of the group hold the sum
}

// ---------------- f16 dot helper ----------------
__device__ __forceinline__ float dotU(const U16& w, const U16& x, float acc) {
#pragma unroll
    for (int i = 0; i < 4; ++i) acc = FDOT2(w.h[i], x.h[i], acc);
    return acc;
}

// ---------------- register weight structs + loaders ----------------
struct WF1  { U16 w[2]; };                        // K=128, NR=1
struct WGRU { U16 wih[6]; U16 whh[3]; U16 glu; }; // 40 VGPRs
struct WSK  { U16 w[10]; };                       // K=320, NR=2
struct WSG  { U16 w[4]; };                        // K=128, NR=2

__device__ __forceinline__ void ldF1(const f16* W, int row, int g, WF1& r) {
    const f16* p = W + row * 128 + g * 16;
    r.w[0].u = *(const uint4*)p;
    r.w[1].u = *(const uint4*)(p + 8);
}
__device__ __forceinline__ void ldF2(const f16* W, int row, int g, U16& r) {
    r.u = *(const uint4*)(W + row * 64 + g * 8);
}
__device__ __forceinline__ void ldGRU(const f16* Wih, const f16* Whh, const f16* Glu,
                                      int row, int g, WGRU& r) {
#pragma unroll
    for (int j = 0; j < 3; ++j) {
        const f16* p = Wih + (row + 64 * j) * 128 + g * 16;
        r.wih[2 * j].u     = *(const uint4*)p;
        r.wih[2 * j + 1].u = *(const uint4*)(p + 8);
        r.whh[j].u = *(const uint4*)(Whh + (row + 64 * j) * 64 + g * 8);
    }
    r.glu.u = *(const uint4*)(Glu + row * 64 + g * 8);
}
__device__ __forceinline__ void ldSK(const f16* W, int row, int g, WSK& r) {
#pragma unroll
    for (int j = 0; j < 2; ++j) {
        const f16* p = W + (row + 64 * j) * 320 + g * 40;
#pragma unroll
        for (int i = 0; i < 5; ++i) r.w[5 * j + i].u = *(const uint4*)(p + 8 * i);
    }
}
__device__ __forceinline__ void ldSG(const f16* W, int row, int g, WSG& r) {
#pragma unroll
    for (int j = 0; j < 2; ++j) {
        const f16* p = W + (row + 64 * j) * 128 + g * 16;
        r.w[2 * j].u     = *(const uint4*)p;
        r.w[2 * j + 1].u = *(const uint4*)(p + 8);
    }
}

// opaque pin: makes the loaded values asm-defined -> cannot be rematerialized
__device__ __forceinline__ void pinU(U16& r) {
    asm volatile("" : "+v"(r.u.x), "+v"(r.u.y), "+v"(r.u.z), "+v"(r.u.w));
}

// ---------------- weight convert to f16 (flat, same layout) ----------------
struct SrcW { const float* p[14]; };

__global__ __launch_bounds__(256) void fargan_cvtw(SrcW s, f16* __restrict__ dst) {
    const int offs[15] = {0, 8192, 12288, 36864, 49152, 53248, 77824, 90112,
                          94208, 118784, 131072, 135168, 176128, 192512, 200704};
    int i = blockIdx.x * 256 + threadIdx.x;
    if (i >= W_TOTAL) return;
    int sgi = 0;
#pragma unroll
    for (int t = 1; t < 14; ++t) sgi += (i >= offs[t]);
    dst[i] = (f16)s.p[sgi][i - offs[sgi]];
}

// ---------------- feature transpose: f[b][c][t] -> fT[t][b][c] ----------------
__global__ __launch_bounds__(256) void fargan_tr(const float* __restrict__ f,
                                                 float* __restrict__ fT) {
    __shared__ float L[64][104];
    int b = blockIdx.x >> 2, c0 = (blockIdx.x & 3) * 64;
    for (int e = threadIdx.x; e < 6400; e += 256) {
        int r = e / 100, col = e - r * 100;
        L[r][col] = f[b * NFC * TT + (c0 + r) * TT + col];
    }
    __syncthreads();
    for (int e = threadIdx.x; e < 6400; e += 256) {
        int t = e >> 6, c = e & 63;
        fT[(t * BB + b) * NFC + c0 + c] = L[c][t];
    }
}

// ---------------- frame input network (fp32) ----------------
__global__ __launch_bounds__(256) void fargan_frame(
    const float* __restrict__ fT, const float* __restrict__ gfeat,
    const float* __restrict__ W1, const float* __restrict__ ib1,
    const float* __restrict__ W2, const float* __restrict__ ib2,
    float* __restrict__ xall)
{
    __shared__ __align__(16) float cat[16][ICC];
    __shared__ __align__(16) float zb[16][ICC];
    const int tid = threadIdx.x;
    const int t = blockIdx.x >> 2;
    const int q = blockIdx.x & 3;

    for (int bb = 0; bb < 16; ++bb) {
        int b = q * 16 + bb;
        for (int c = tid; c < ICC; c += 256) {
            float v = (c < NFC) ? fT[(t * BB + b) * NFC + c]
                                : gfeat[b * GCC + (c - NFC)];
            cat[bb][c] = v;
        }
    }
    __syncthreads();

    {
        int rg = tid & 63, bg = tid >> 6;
        int n0 = rg * 8, bb0 = bg * 4;
        float acc[8][4];
#pragma unroll
        for (int r = 0; r < 8; ++r)
#pragma unroll
            for (int j = 0; j < 4; ++j) acc[r][j] = 0.f;
        for (int k = 0; k < ICC; k += 4) {
            float4 cv[4];
#pragma unroll
            for (int j = 0; j < 4; ++j) cv[j] = *(const float4*)&cat[bb0 + j][k];
#pragma unroll
            for (int r = 0; r < 8; ++r) {
                float4 wv = *(const float4*)&W1[(n0 + r) * ICC + k];
#pragma unroll
                for (int j = 0; j < 4; ++j)
                    acc[r][j] += wv.x * cv[j].x + wv.y * cv[j].y + wv.z * cv[j].z + wv.w * cv[j].w;
            }
        }
#pragma unroll
        for (int r = 0; r < 8; ++r) {
            float bias = ib1[n0 + r];
#pragma unroll
            for (int j = 0; j < 4; ++j)
                zb[bb0 + j][n0 + r] = tanhf(acc[r][j] + bias);
        }
    }
    __syncthreads();

    {
        int rg = tid & 63, bg = tid >> 6;
        int n0 = rg * 4, bb0 = bg * 4;
        float acc[4][4];
#pragma unroll
        for (int r = 0; r < 4; ++r)
#pragma unroll
            for (int j = 0; j < 4; ++j) acc[r][j] = 0.f;
        for (int k = 0; k < ICC; k += 4) {
            float4 cv[4];
#pragma unroll
            for (int j = 0; j < 4; ++j) cv[j] = *(const float4*)&zb[bb0 + j][k];
#pragma unroll
            for (int r = 0; r < 4; ++r) {
                float4 wv = *(const float4*)&W2[(n0 + r) * ICC + k];
#pragma unroll
                for (int j = 0; j < 4; ++j)
                    acc[r][j] += wv.x * cv[j].x + wv.y * cv[j].y + wv.z * cv[j].z + wv.w * cv[j].w;
            }
        }
#pragma unroll
        for (int r = 0; r < 4; ++r) {
            float bias = ib2[n0 + r];
#pragma unroll
            for (int j = 0; j < 4; ++j) {
                int b = q * 16 + bb0 + j;
                xall[(t * BB + b) * HOPC + n0 + r] = acc[r][j] + bias;
            }
        }
    }
}

// ---------------- sequential chain: pinned regs, DPP reduce, 11 barriers ----
__global__ __launch_bounds__(512, 2) void fargan_seq(
    const float* __restrict__ xall, const f16* __restrict__ wh,
    float* __restrict__ outp)
{
    const int tid = threadIdx.x;
    const int row = tid >> 3;
    const int g = tid & 7;
    const int bg = blockIdx.x;          // chain id

    __shared__ __align__(16) f16 XH[128];          // xsub|s3 mirrors
    __shared__ __align__(16) f16 SKXH[320];        // g1|g2|g3|fw|prevN
    __shared__ __align__(16) f16 TWH[64], HNH[64];
    __shared__ __align__(16) f16 SPNH[128], SKVH[128];
    __shared__ __align__(16) f16 HH[2][3][64];     // GRU state f16 mirrors (ping-pong)
    __shared__ __align__(16) float Hf[2][3][64];   // GRU state fp32 (ping-pong)
    __shared__ __align__(16) float UNF[704];
    __shared__ uint32_t kkb[2][20];                // keys ping-pong

    // ---- one-time: register weights (pinned) + init
    WF1 rF1;  ldF1(wh + OFF_FW, row, g, rF1);
    U16 rF2;  ldF2(wh + OFF_FWGLU, row, g, rF2);
    WGRU rG1; ldGRU(wh + OFF_G1IH, wh + OFF_G1HH, wh + OFF_GLU1, row, g, rG1);
    WGRU rG2; ldGRU(wh + OFF_G2IH, wh + OFF_G2HH, wh + OFF_GLU2, row, g, rG2);
    WGRU rG3; ldGRU(wh + OFF_G3IH, wh + OFF_G3HH, wh + OFF_GLU3, row, g, rG3);
    WSG rSG;  ldSG(wh + OFF_SKIPG, row, g, rSG);
    WF1 rOUT; ldF1(wh + OFF_OUT, row, g, rOUT);

    pinU(rF1.w[0]); pinU(rF1.w[1]); pinU(rF2);
#pragma unroll
    for (int j = 0; j < 6; ++j) { pinU(rG1.wih[j]); pinU(rG2.wih[j]); pinU(rG3.wih[j]); }
#pragma unroll
    for (int j = 0; j < 3; ++j) { pinU(rG1.whh[j]); pinU(rG2.whh[j]); pinU(rG3.whh[j]); }
    pinU(rG1.glu); pinU(rG2.glu); pinU(rG3.glu);
#pragma unroll
    for (int j = 0; j < 4; ++j) pinU(rSG.w[j]);
    pinU(rOUT.w[0]); pinU(rOUT.w[1]);

    float prevO = 0.f, xs_old = 0.f;
    if (g == 0) {
#pragma unroll
        for (int i = 0; i < 3; ++i) { Hf[0][i][row] = 0.f; HH[0][i][row] = (f16)0.f; }
        XH[row] = (f16)0.f; XH[64 + row] = (f16)0.f;
    }
    if (tid < 10) {   // keys for idx 0
        uint32_t f0, f1; tf2x32(0u, 1u, 0u, 0u, f0, f1);
        uint32_t A, Bv;  tf2x32(f0, f1, 0u, (uint32_t)tid, A, Bv);
        kkb[0][2 * tid] = A; kkb[0][2 * tid + 1] = Bv;
    }
    __syncthreads();

    for (int t = 0; t < TT; ++t) {
        for (int s = 0; s < 4; ++s) {
            const int idx = t * 4 + s;
            const int p = idx & 1;

            // ======== A: uniforms + input/prev noise + next keys  [barrier 1]
            float xv = xall[(t * BB + bg) * HOPC + s * SS + row];
            if (g == 0) {
                const uint32_t m64 = (uint32_t)(bg * 64 + row);
                float u0 = unifP(kkb[p][0], kkb[p][1], m64);
                float u1 = unifP(kkb[p][2], kkb[p][3], m64);
                float xs = noiseu(xv, u0);
                XH[row] = (f16)xs; XH[64 + row] = (f16)xs_old; xs_old = xs;
                SKXH[256 + row] = (f16)noiseu(prevO, u1);
            } else {
                int wid = row * 7 + g - 1;          // 0..447
                int j = 128 + wid;                  // slots 2..8
                int sl = j >> 6;
                UNF[j] = unifP(kkb[p][2 * sl], kkb[p][2 * sl + 1],
                               (uint32_t)(bg * 64 + (j & 63)));
                if (wid < 128)                       // slots 9..10 (skip, 128 vals)
                    UNF[576 + wid] = unifP(kkb[p][18], kkb[p][19],
                                           (uint32_t)(bg * 128 + wid));
            }
            if (g == 7 && row >= 54) {               // keys for idx+1
                int i = row - 54;
                uint32_t f0, f1; tf2x32(0u, 1u, 0u, (uint32_t)(idx + 1), f0, f1);
                uint32_t A, Bv;  tf2x32(f0, f1, 0u, (uint32_t)i, A, Bv);
                kkb[p ^ 1][2 * i] = A; kkb[p ^ 1][2 * i + 1] = Bv;
            }
            __syncthreads();

            // ======== FW1: tw = tanh(fw_W @ [xsub; s3])            [barrier 2]
            float twv;
            {
                U16 xa, xb;
                xa.u = *(const uint4*)&XH[g * 16];
                xb.u = *(const uint4*)&XH[g * 16 + 8];
                float a = dotU(rF1.w[0], xa, 0.f);
                a = dotU(rF1.w[1], xb, a);
                twv = tanhfast(red8dpp(a));
                if (g == 0) TWH[row] = (f16)twv;
            }
            __syncthreads();

            // ======== FW2: fw = noise(tw * sigm(fw_glu @ tw))      [barrier 3]
            {
                U16 xa; xa.u = *(const uint4*)&TWH[g * 8];
                float a = red8dpp(dotU(rF2, xa, 0.f));
                if (g == 0) SKXH[192 + row] = (f16)noiseu(twv * sigmf(a), UNF[128 + row]);
            }
            __syncthreads();

            // ======== GRU+GLU x3 (2 barriers each)
#define GRU_STEP(RG, XPTR, GI, UH, UG, GOFF)                                               \
            {                                                                               \
                const f16* xin = (XPTR);                                                    \
                U16 xa, xb, xh;                                                             \
                xa.u = *(const uint4*)xin;                                                  \
                xb.u = *(const uint4*)(xin + 8);                                            \
                xh.u = *(const uint4*)&HH[p][GI][g * 8];                                    \
                float ai0 = 0, ai1 = 0, ai2 = 0, ah0 = 0, ah1 = 0, ah2 = 0;                 \
                ai0 = dotU(RG.wih[0], xa, ai0); ai0 = dotU(RG.wih[1], xb, ai0);             \
                ai1 = dotU(RG.wih[2], xa, ai1); ai1 = dotU(RG.wih[3], xb, ai1);             \
                ai2 = dotU(RG.wih[4], xa, ai2); ai2 = dotU(RG.wih[5], xb, ai2);             \
                ah0 = dotU(RG.whh[0], xh, ah0);                                             \
                ah1 = dotU(RG.whh[1], xh, ah1);                                             \
                ah2 = dotU(RG.whh[2], xh, ah2);                                             \
                ai0 = red8dpp(ai0); ai1 = red8dpp(ai1); ai2 = red8dpp(ai2);                 \
                ah0 = red8dpp(ah0); ah1 = red8dpp(ah1); ah2 = red8dpp(ah2);                 \
                float hold = Hf[p][GI][row];                                                \
                float r  = sigmf(ai0 + ah0);                                                \
                float z  = sigmf(ai1 + ah1);                                                \
                float nn = tanhfast(ai2 + r * ah2);                                         \
                float hnew = (1.f - z) * nn + z * hold;                                     \
                float hNv = noiseu(hnew, UNF[(UH) + row]);                                  \
                if (g == 0) {                                                               \
                    Hf[p ^ 1][GI][row] = hnew;                                              \
                    HH[p ^ 1][GI][row] = (f16)hnew;                                         \
                    HNH[row] = (f16)hNv;                                                    \
                }                                                                           \
                __syncthreads();                                                            \
                U16 xg; xg.u = *(const uint4*)&HNH[g * 8];                                  \
                float ag = red8dpp(dotU(RG.glu, xg, 0.f));                                  \
                if (g == 0) SKXH[(GOFF) + row] =                                            \
                    (f16)noiseu(hNv * sigmf(ag), UNF[(UG) + row]);                          \
            }                                                                               \
            __syncthreads();

            GRU_STEP(rG1, SKXH + 192 + g * 16, 0, 192, 256, 0)
            GRU_STEP(rG2, (g < 4 ? SKXH + g * 16 : SKXH + 256 + (g - 4) * 16), 1, 320, 384, 64)
            WSK rSK; ldSK(wh + OFF_SKIPD, row, g, rSK);   // prefetch skip_dense (2 phases early)
            GRU_STEP(rG3, (g < 4 ? SKXH + 64 + g * 16 : SKXH + 256 + (g - 4) * 16), 2, 448, 512, 128)
#undef GRU_STEP

            // ======== SKIP: spN = noise(tanh(skip_dense @ SKXH))   [barrier 10]
            float sp0, sp1;
            {
                U16 xs[5];
#pragma unroll
                for (int i = 0; i < 5; ++i) xs[i].u = *(const uint4*)&SKXH[g * 40 + 8 * i];
                float a0 = 0, a1 = 0;
#pragma unroll
                for (int i = 0; i < 5; ++i) {
                    a0 = dotU(rSK.w[i], xs[i], a0);
                    a1 = dotU(rSK.w[5 + i], xs[i], a1);
                }
                sp0 = noiseu(tanhfast(red8dpp(a0)), UNF[576 + row]);
                sp1 = noiseu(tanhfast(red8dpp(a1)), UNF[640 + row]);
                if (g == 0) { SPNH[row] = (f16)sp0; SPNH[64 + row] = (f16)sp1; }
            }
            __syncthreads();

            // ======== SG: skip = spN * sigm(skip_glu @ spN)        [barrier 11]
            {
                U16 xa, xb;
                xa.u = *(const uint4*)&SPNH[g * 16];
                xb.u = *(const uint4*)&SPNH[g * 16 + 8];
                float a0 = dotU(rSG.w[0], xa, 0.f); a0 = dotU(rSG.w[1], xb, a0);
                float a1 = dotU(rSG.w[2], xa, 0.f); a1 = dotU(rSG.w[3], xb, a1);
                a0 = red8dpp(a0); a1 = red8dpp(a1);
                if (g == 0) {
                    SKVH[row]      = (f16)(sp0 * sigmf(a0));
                    SKVH[64 + row] = (f16)(sp1 * sigmf(a1));
                }
            }
            __syncthreads();

            // ======== OUT: o = tanh(out_W @ skip)   [no barrier]
            {
                U16 xa, xb;
                xa.u = *(const uint4*)&SKVH[g * 16];
                xb.u = *(const uint4*)&SKVH[g * 16 + 8];
                float a = dotU(rOUT.w[0], xa, 0.f);
                a = dotU(rOUT.w[1], xb, a);
                float o = tanhfast(red8dpp(a));
                prevO = o;
                if (g == 0) outp[bg * (TT * HOPC) + t * HOPC + s * SS + row] = o;
            }
        }
    }
}

extern "C" void kernel_launch(void* const* d_in, const int* in_sizes, int n_in,
                              void* d_out, int out_size, void* d_ws, size_t ws_size,
                              hipStream_t stream) {
    const float* features = (const float*)d_in[0];
    const float* gfeat    = (const float*)d_in[1];
    const float* W1       = (const float*)d_in[2];
    const float* ib1      = (const float*)d_in[3];
    const float* W2       = (const float*)d_in[4];
    const float* ib2      = (const float*)d_in[5];

    float* xall = (float*)d_ws;                    // 6.55 MB
    float* fT   = xall + XALL_F32;                 // 6.55 MB
    f16*   wh   = (f16*)(fT + XALL_F32);           // 0.40 MB
    float* outp = (float*)d_out;

    SrcW sw;
    for (int i = 0; i < 14; ++i) sw.p[i] = (const float*)d_in[6 + i];

    hipLaunchKernelGGL(fargan_cvtw, dim3((W_TOTAL + 255) / 256), dim3(256), 0, stream, sw, wh);
    hipLaunchKernelGGL(fargan_tr, dim3(256), dim3(256), 0, stream, features, fT);
    hipLaunchKernelGGL(fargan_frame, dim3(TT * 4), dim3(256), 0, stream,
                       fT, gfeat, W1, ib1, W2, ib2, xall);
    hipLaunchKernelGGL(fargan_seq, dim3(NBLK), dim3(NTHR), 0, stream, xall, wh, outp);
}